// Round 8
// baseline (275.060 us; speedup 1.0000x reference)
//
#include <hip/hip_runtime.h>
#include <hip/hip_bf16.h>

#define C_ 256
#define N_ 4096
#define B_ 4
#define NG_ 32
#define CPG_ 8
#define SPLITS 2
#define JT_PER (N_ / 32 / SPLITS)   // 64 j-tiles of 32 per split

typedef _Float16 f16;
typedef __attribute__((ext_vector_type(8))) _Float16 f16v8;
typedef __attribute__((ext_vector_type(2))) __fp16 fp16v2;
typedef __attribute__((ext_vector_type(4))) float f32x4;

__device__ __forceinline__ f16v8 ldh(const f16* p) {
    return *reinterpret_cast<const f16v8*>(p);
}
__device__ __forceinline__ f32x4 mfma16(f16v8 a, f16v8 b, f32x4 c) {
    return __builtin_amdgcn_mfma_f32_16x16x32_f16(a, b, c, 0, 0, 0);
}
__device__ __forceinline__ unsigned int pkh(float a, float b) {
    fp16v2 t = __builtin_amdgcn_cvt_pkrtz(a, b);
    return __builtin_bit_cast(unsigned int, t);
}

// ---------------- 0. weights fp32 -> fp16 ----------------
__global__ __launch_bounds__(256) void conv_w_kernel(
    const float* __restrict__ wq, const float* __restrict__ wk,
    const float* __restrict__ wv, const float* __restrict__ wo,
    f16* __restrict__ wq16, f16* __restrict__ wk16,
    f16* __restrict__ wv16, f16* __restrict__ wo16)
{
    int idx = blockIdx.x * 256 + threadIdx.x;   // 65536 elements
    wq16[idx] = (f16)wq[idx];
    wk16[idx] = (f16)wk[idx];
    wv16[idx] = (f16)wv[idx];
    wo16[idx] = (f16)wo[idx];
}

// ---------------- 1. GroupNorm -> hn^T [b][n][c] fp16 ----------------
__global__ __launch_bounds__(256) void gn_kernel(
    const float* __restrict__ x, const float* __restrict__ gamma,
    const float* __restrict__ beta, f16* __restrict__ hn)
{
    int b = blockIdx.x >> 5, g = blockIdx.x & 31;
    const float* xp = x + (size_t)(b * C_ + g * CPG_) * N_;
    int tid = threadIdx.x;
    float s = 0.f, s2 = 0.f;
    for (int idx = tid; idx < CPG_ * N_; idx += 256) {
        float v = xp[idx];
        s += v; s2 += v * v;
    }
    #pragma unroll
    for (int off = 32; off > 0; off >>= 1) {
        s  += __shfl_down(s, off);
        s2 += __shfl_down(s2, off);
    }
    __shared__ float rs[4], rs2[4], stat[2];
    if ((tid & 63) == 0) { rs[tid >> 6] = s; rs2[tid >> 6] = s2; }
    __syncthreads();
    if (tid == 0) {
        float S  = rs[0] + rs[1] + rs[2] + rs[3];
        float S2 = rs2[0] + rs2[1] + rs2[2] + rs2[3];
        float mean = S / (float)(CPG_ * N_);
        float var  = S2 / (float)(CPG_ * N_) - mean * mean;
        stat[0] = mean;
        stat[1] = rsqrtf(var + 1e-6f);
    }
    __syncthreads();
    float mean = stat[0], rstd = stat[1];
    float ga[CPG_], be[CPG_];
    #pragma unroll
    for (int cc = 0; cc < CPG_; cc++) {
        ga[cc] = gamma[g * CPG_ + cc] * rstd;
        be[cc] = beta[g * CPG_ + cc];
    }
    for (int i = tid; i < N_; i += 256) {
        f16v8 H;
        #pragma unroll
        for (int cc = 0; cc < CPG_; cc++)
            H[cc] = (f16)((xp[(size_t)cc * N_ + i] - mean) * ga[cc] + be[cc]);
        *reinterpret_cast<f16v8*>(hn + (size_t)(b * N_ + i) * C_ + g * CPG_) = H;
    }
}

// ---------------- 2. q/k/v projection (z selects matrix; 32-row tiles) -----
// wave w: rows i0 = it*32 + (w&1)*16, oc-tiles [(w>>1)*8, +8)
__global__ __launch_bounds__(256) void proj_kernel(
    const f16* __restrict__ hn, const f16* __restrict__ wq16,
    const f16* __restrict__ wk16, const f16* __restrict__ wv16,
    const float* __restrict__ bq, const float* __restrict__ bk,
    const float* __restrict__ bv,
    f16* __restrict__ qo, f16* __restrict__ ko, f16* __restrict__ vt)
{
    int it = blockIdx.x, b = blockIdx.y, which = blockIdx.z;
    int tid = threadIdx.x, w = tid >> 6, l = tid & 63;
    int l15 = l & 15, lhi = l >> 4;
    int i0 = it * 32 + (w & 1) * 16;
    int oc0 = (w >> 1) * 8;

    size_t arow = (size_t)(b * N_ + i0 + l15) * C_ + lhi * 8;
    f16v8 af[8];
    #pragma unroll
    for (int kk = 0; kk < 8; kk++) af[kk] = ldh(hn + arow + kk * 32);

    if (which < 2) {
        const f16* wgt = which ? wk16 : wq16;
        const float* bias = which ? bk : bq;
        f16* outp = which ? ko : qo;
        for (int oc = oc0; oc < oc0 + 8; oc++) {
            f32x4 acc = {0.f, 0.f, 0.f, 0.f};
            size_t wrow = (size_t)(oc * 16 + l15) * C_ + lhi * 8;
            #pragma unroll
            for (int kk = 0; kk < 8; kk++)
                acc = mfma16(af[kk], ldh(wgt + wrow + kk * 32), acc);
            float bia = bias[oc * 16 + l15];
            #pragma unroll
            for (int r = 0; r < 4; r++)
                outp[(size_t)(b * N_ + i0 + lhi * 4 + r) * C_ + oc * 16 + l15] =
                    (f16)(acc[r] + bia);
        }
    } else {
        // v: D[c_out][i] (weights as A-operand) -> vT [b][c][n]
        for (int oc = oc0; oc < oc0 + 8; oc++) {
            f32x4 acc = {0.f, 0.f, 0.f, 0.f};
            size_t wrow = (size_t)(oc * 16 + l15) * C_ + lhi * 8;
            #pragma unroll
            for (int kk = 0; kk < 8; kk++)
                acc = mfma16(ldh(wv16 + wrow + kk * 32), af[kk], acc);
            #pragma unroll
            for (int r = 0; r < 4; r++) {
                int o = oc * 16 + lhi * 4 + r;
                vt[(size_t)(b * C_ + o) * N_ + i0 + l15] = (f16)(acc[r] + bv[o]);
            }
        }
    }
}

// ---------------- 3. flash attention: fragment-major LDS tiles --------------
// K tile (32j x 256k): chunk id = (jc*8+kk)*64 + lane; lane reads back
// base + (jc*8+kk)*1024B + l*16B -> canonical conflict-free b128.
__device__ __forceinline__ void stage_k(const f16* kbase, f16* dst, int j0,
                                        int w, int l) {
    #pragma unroll
    for (int rd = 0; rd < 4; rd++) {
        int grp = rd * 4 + w;                       // wave-uniform 0..15
        int row = (grp >> 3) * 16 + (l & 15);
        int col = (grp & 7) * 32 + (l >> 4) * 8;
        const f16* gsrc = kbase + (size_t)(j0 + row) * C_ + col;
        __builtin_amdgcn_global_load_lds(
            (const __attribute__((address_space(1))) void*)gsrc,
            (__attribute__((address_space(3))) void*)(dst + (size_t)grp * 512),
            16, 0, 0);
    }
}
// V tile (256c x 32j): chunk id = cc*64 + lane
__device__ __forceinline__ void stage_v(const f16* vbase, f16* dst, int j0,
                                        int w, int l) {
    #pragma unroll
    for (int rd = 0; rd < 4; rd++) {
        int cc = rd * 4 + w;                        // wave-uniform 0..15
        const f16* gsrc = vbase + (size_t)(cc * 16 + (l & 15)) * N_
                          + j0 + (l >> 4) * 8;
        __builtin_amdgcn_global_load_lds(
            (const __attribute__((address_space(1))) void*)gsrc,
            (__attribute__((address_space(3))) void*)(dst + (size_t)cc * 512),
            16, 0, 0);
    }
}

__global__ __launch_bounds__(256, 2) void flash_split_kernel(
    const f16* __restrict__ q, const f16* __restrict__ k,
    const f16* __restrict__ vT,
    f16* __restrict__ o0p, f16* __restrict__ o1p,
    float2* __restrict__ stats)
{
    // XCD-pinned: linear id % 8 -> XCD; group = (b,split), 2MB K/V L2-resident.
    int bi = blockIdx.x;
    int g = bi & 7;
    int it = bi >> 3;                 // 0..63
    int b = g >> 1, split = g & 1;
    int tid = threadIdx.x, w = tid >> 6, l = tid & 63;
    int l15 = l & 15, lhi = l >> 4;
    int i0 = it * 64 + w * 16;
    int jt0 = split * JT_PER;
    __shared__ __align__(16) f16 kb[2][16][512];     // 32 KB, fragment-major
    __shared__ __align__(16) f16 vb[2][16][512];     // 32 KB, fragment-major
    __shared__ __align__(16) unsigned int Plds[4][16][20];  // 5 KB

    const f16* kbase = k + (size_t)b * N_ * C_;
    const f16* vbase = vT + (size_t)b * C_ * N_;

    f16v8 qf[8];
    size_t qrow = (size_t)(b * N_ + i0 + l15) * C_ + lhi * 8;
    #pragma unroll
    for (int kk = 0; kk < 8; kk++) qf[kk] = ldh(q + qrow + kk * 32);

    // oacc[cc][r] = O^T[c = cc*16 + lhi*4 + r][i = i0 + l15]
    f32x4 oacc[16];
    #pragma unroll
    for (int cc = 0; cc < 16; cc++) oacc[cc] = (f32x4){0.f, 0.f, 0.f, 0.f};
    float m = -1e30f, rsum = 0.f;    // per-lane: row i = i0 + l15

    stage_k(kbase, &kb[0][0][0], jt0 * 32, w, l);
    stage_v(vbase, &vb[0][0][0], jt0 * 32, w, l);
    __syncthreads();

    for (int jt = 0; jt < JT_PER; jt++) {
        int cur = jt & 1;
        int j0 = (jt0 + jt) * 32;

        if (jt + 1 < JT_PER) {
            stage_k(kbase, &kb[cur ^ 1][0][0], j0 + 32, w, l);
            stage_v(vbase, &vb[cur ^ 1][0][0], j0 + 32, w, l);
        }

        // ---- swapped QK^T: s'[j][i] = mfma(K, Q) ----
        const f16* kbc = &kb[cur][0][0] + l * 8;
        f32x4 s0 = {0.f, 0.f, 0.f, 0.f};
        f32x4 s1 = {0.f, 0.f, 0.f, 0.f};
        __builtin_amdgcn_s_setprio(1);
        #pragma unroll
        for (int kk = 0; kk < 8; kk++) {
            f16v8 kf0 = ldh(kbc + kk * 512);
            f16v8 kf1 = ldh(kbc + (8 + kk) * 512);
            s0 = mfma16(kf0, qf[kk], s0);
            s1 = mfma16(kf1, qf[kk], s1);
        }
        __builtin_amdgcn_s_setprio(0);

        // ---- per-lane online softmax with defer-max (THR=8) ----
        float mt = fmaxf(fmaxf(fmaxf(s0[0], s0[1]), fmaxf(s0[2], s0[3])),
                         fmaxf(fmaxf(s1[0], s1[1]), fmaxf(s1[2], s1[3])));
        mt = fmaxf(mt, __shfl_xor(mt, 16));
        mt = fmaxf(mt, __shfl_xor(mt, 32));
        if (!__all(mt <= m + 8.f)) {
            float mn = fmaxf(m, mt);
            float sc = __expf(m - mn);
            m = mn;
            rsum *= sc;
            #pragma unroll
            for (int cc = 0; cc < 16; cc++) {
                #pragma unroll
                for (int r = 0; r < 4; r++) oacc[cc][r] *= sc;
            }
        }
        float p0[4], p1[4];
        float ls = 0.f;
        #pragma unroll
        for (int r = 0; r < 4; r++) {
            p0[r] = __expf(s0[r] - m);
            p1[r] = __expf(s1[r] - m);
            ls += p0[r] + p1[r];
        }
        rsum += ls;

        // ---- P' -> LDS transposed (wave-local; lgkm-ordered, no barrier) ----
        uint2 pa = {pkh(p0[0], p0[1]), pkh(p0[2], p0[3])};
        uint2 pb = {pkh(p1[0], p1[1]), pkh(p1[2], p1[3])};
        *reinterpret_cast<uint2*>(&Plds[w][l15][lhi * 2])     = pa;
        *reinterpret_cast<uint2*>(&Plds[w][l15][8 + lhi * 2]) = pb;
        f16v8 pfB = *reinterpret_cast<const f16v8*>(&Plds[w][l15][lhi * 4]);

        // ---- O^T += V^T @ P' (fragment-major LDS, conflict-free) ----
        const f16* vbc = &vb[cur][0][0] + l * 8;
        __builtin_amdgcn_s_setprio(1);
        #pragma unroll
        for (int cc = 0; cc < 16; cc++) {
            f16v8 vf = ldh(vbc + cc * 512);
            oacc[cc] = mfma16(vf, pfB, oacc[cc]);
        }
        __builtin_amdgcn_s_setprio(0);

        __syncthreads();   // drains stage(jt+1) vmcnt; WAR guard for cur buffers
    }

    // final cross-lane lsum reduce (4 lanes share row i)
    rsum += __shfl_xor(rsum, 16);
    rsum += __shfl_xor(rsum, 32);
    float inv = 1.f / rsum;

    f16* op = split ? o1p : o0p;
    size_t obase = (size_t)(b * N_ + i0 + l15) * C_;
    #pragma unroll
    for (int cc = 0; cc < 16; cc++) {
        uint2 st = {pkh(oacc[cc][0] * inv, oacc[cc][1] * inv),
                    pkh(oacc[cc][2] * inv, oacc[cc][3] * inv)};
        *reinterpret_cast<uint2*>(op + obase + cc * 16 + lhi * 4) = st;
    }
    if (lhi == 0)
        stats[((size_t)split * B_ + b) * N_ + i0 + l15] = make_float2(m, rsum);
}

// ---------------- 4. fused combine + conv_o + bias + residual ---------------
// wave w: rows i0 = it*32 + (w&1)*16 (one fragment), o-cols [(w>>1)*128, +128)
__global__ __launch_bounds__(256) void final_kernel(
    const f16* __restrict__ o0p, const f16* __restrict__ o1p,
    const float2* __restrict__ stats, const f16* __restrict__ wo16,
    const float* __restrict__ bo, const float* __restrict__ x,
    float* __restrict__ out)
{
    int it = blockIdx.x, b = blockIdx.y;
    int tid = threadIdx.x, w = tid >> 6, l = tid & 63;
    int l15 = l & 15, lhi = l >> 4;
    int i0 = it * 32 + (w & 1) * 16;
    int ob = (w >> 1) * 128;

    // per-row split weights (row = i0 + l15)
    int row = i0 + l15;
    float2 st0 = stats[(size_t)b * N_ + row];
    float2 st1 = stats[((size_t)B_ + b) * N_ + row];
    float M = fmaxf(st0.x, st1.x);
    float a0 = st0.y * __expf(st0.x - M);
    float a1 = st1.y * __expf(st1.x - M);
    float winv = 1.f / (a0 + a1);
    f16 w0h = (f16)(a0 * winv);
    f16 w1h = (f16)(a1 * winv);

    f32x4 acc[8];
    #pragma unroll
    for (int mc = 0; mc < 8; mc++) acc[mc] = (f32x4){0.f, 0.f, 0.f, 0.f};
    for (int kk = 0; kk < 8; kk++) {
        size_t off = (size_t)(b * N_ + i0 + l15) * C_ + kk * 32 + lhi * 8;
        f16v8 a = ldh(o0p + off);
        f16v8 c = ldh(o1p + off);
        f16v8 bfv = a * w0h + c * w1h;
        #pragma unroll
        for (int mc = 0; mc < 8; mc++) {
            f16v8 af = ldh(wo16 + (size_t)(ob + mc * 16 + l15) * C_ + kk * 32 + lhi * 8);
            acc[mc] = mfma16(af, bfv, acc[mc]);
        }
    }
    #pragma unroll
    for (int mc = 0; mc < 8; mc++) {
        #pragma unroll
        for (int r = 0; r < 4; r++) {
            int o = ob + mc * 16 + lhi * 4 + r;
            int i = i0 + l15;
            size_t idx = (size_t)(b * C_ + o) * N_ + i;
            out[idx] = x[idx] + acc[mc][r] + bo[o];
        }
    }
}

extern "C" void kernel_launch(void* const* d_in, const int* in_sizes, int n_in,
                              void* d_out, int out_size, void* d_ws, size_t ws_size,
                              hipStream_t stream) {
    const float* x  = (const float*)d_in[0];
    const float* gg = (const float*)d_in[1];
    const float* gb = (const float*)d_in[2];
    const float* wq = (const float*)d_in[3];
    const float* bq = (const float*)d_in[4];
    const float* wk = (const float*)d_in[5];
    const float* bk = (const float*)d_in[6];
    const float* wv = (const float*)d_in[7];
    const float* bv = (const float*)d_in[8];
    const float* wo = (const float*)d_in[9];
    const float* bo = (const float*)d_in[10];
    float* out = (float*)d_out;

    char* p = (char*)d_ws;
    const size_t WSZ = (size_t)C_ * C_ * 2;       // 128 KB per fp16 weight
    const size_t HSZ = (size_t)B_ * N_ * C_ * 2;  // 8 MB per fp16 activation
    f16* wq16 = (f16*)p; p += WSZ;
    f16* wk16 = (f16*)p; p += WSZ;
    f16* wv16 = (f16*)p; p += WSZ;
    f16* wo16 = (f16*)p; p += WSZ;
    f16* hn   = (f16*)p; p += HSZ;
    f16* qo   = (f16*)p; p += HSZ;
    f16* ko   = (f16*)p; p += HSZ;
    f16* vt   = (f16*)p; p += HSZ;
    f16* o1p  = (f16*)p; p += HSZ;                // split-1 partial
    float2* stats = (float2*)p; p += (size_t)SPLITS * B_ * N_ * sizeof(float2);

    f16* o0p = hn;            // hn dead after projections; split-0 partial

    conv_w_kernel<<<dim3(C_ * C_ / 256), 256, 0, stream>>>(
        wq, wk, wv, wo, wq16, wk16, wv16, wo16);
    gn_kernel<<<dim3(B_ * NG_), 256, 0, stream>>>(x, gg, gb, hn);
    proj_kernel<<<dim3(N_ / 32, B_, 3), 256, 0, stream>>>(
        hn, wq16, wk16, wv16, bq, bk, bv, qo, ko, vt);
    flash_split_kernel<<<dim3(N_ / 64 * B_ * SPLITS), 256, 0, stream>>>(
        qo, ko, vt, o0p, o1p, stats);
    final_kernel<<<dim3(N_ / 32, B_), 256, 0, stream>>>(
        o0p, o1p, stats, wo16, bo, x, out);
}

// Round 9
// 217.869 us; speedup vs baseline: 1.2625x; 1.2625x over previous
//
#include <hip/hip_runtime.h>
#include <hip/hip_bf16.h>

#define C_ 256
#define N_ 4096
#define B_ 4
#define NG_ 32
#define CPG_ 8
#define SPLITS 2
#define JT_PER (N_ / 32 / SPLITS)   // 64 j-tiles of 32 per split

typedef _Float16 f16;
typedef __attribute__((ext_vector_type(8))) _Float16 f16v8;
typedef __attribute__((ext_vector_type(2))) __fp16 fp16v2;
typedef __attribute__((ext_vector_type(4))) float f32x4;

__device__ __forceinline__ f16v8 ldh(const f16* p) {
    return *reinterpret_cast<const f16v8*>(p);
}
__device__ __forceinline__ f32x4 mfma16(f16v8 a, f16v8 b, f32x4 c) {
    return __builtin_amdgcn_mfma_f32_16x16x32_f16(a, b, c, 0, 0, 0);
}
__device__ __forceinline__ unsigned int pkh(float a, float b) {
    fp16v2 t = __builtin_amdgcn_cvt_pkrtz(a, b);
    return __builtin_bit_cast(unsigned int, t);
}

// ---------------- 0. weights fp32 -> fp16 ----------------
__global__ __launch_bounds__(256) void conv_w_kernel(
    const float* __restrict__ wq, const float* __restrict__ wk,
    const float* __restrict__ wv, const float* __restrict__ wo,
    f16* __restrict__ wq16, f16* __restrict__ wk16,
    f16* __restrict__ wv16, f16* __restrict__ wo16)
{
    int idx = blockIdx.x * 256 + threadIdx.x;   // 65536 elements
    wq16[idx] = (f16)wq[idx];
    wk16[idx] = (f16)wk[idx];
    wv16[idx] = (f16)wv[idx];
    wo16[idx] = (f16)wo[idx];
}

// ---------------- 1. GroupNorm -> hn^T [b][n][c] fp16 ----------------
__global__ __launch_bounds__(256) void gn_kernel(
    const float* __restrict__ x, const float* __restrict__ gamma,
    const float* __restrict__ beta, f16* __restrict__ hn)
{
    int b = blockIdx.x >> 5, g = blockIdx.x & 31;
    const float* xp = x + (size_t)(b * C_ + g * CPG_) * N_;
    int tid = threadIdx.x;
    float s = 0.f, s2 = 0.f;
    for (int idx = tid; idx < CPG_ * N_; idx += 256) {
        float v = xp[idx];
        s += v; s2 += v * v;
    }
    #pragma unroll
    for (int off = 32; off > 0; off >>= 1) {
        s  += __shfl_down(s, off);
        s2 += __shfl_down(s2, off);
    }
    __shared__ float rs[4], rs2[4], stat[2];
    if ((tid & 63) == 0) { rs[tid >> 6] = s; rs2[tid >> 6] = s2; }
    __syncthreads();
    if (tid == 0) {
        float S  = rs[0] + rs[1] + rs[2] + rs[3];
        float S2 = rs2[0] + rs2[1] + rs2[2] + rs2[3];
        float mean = S / (float)(CPG_ * N_);
        float var  = S2 / (float)(CPG_ * N_) - mean * mean;
        stat[0] = mean;
        stat[1] = rsqrtf(var + 1e-6f);
    }
    __syncthreads();
    float mean = stat[0], rstd = stat[1];
    float ga[CPG_], be[CPG_];
    #pragma unroll
    for (int cc = 0; cc < CPG_; cc++) {
        ga[cc] = gamma[g * CPG_ + cc] * rstd;
        be[cc] = beta[g * CPG_ + cc];
    }
    for (int i = tid; i < N_; i += 256) {
        f16v8 H;
        #pragma unroll
        for (int cc = 0; cc < CPG_; cc++)
            H[cc] = (f16)((xp[(size_t)cc * N_ + i] - mean) * ga[cc] + be[cc]);
        *reinterpret_cast<f16v8*>(hn + (size_t)(b * N_ + i) * C_ + g * CPG_) = H;
    }
}

// ---------------- 2. q/k projection ----------------
__global__ __launch_bounds__(256) void proj_qk_kernel(
    const f16* __restrict__ hn, const f16* __restrict__ wq16,
    const f16* __restrict__ wk16, const float* __restrict__ bq,
    const float* __restrict__ bk, f16* __restrict__ qo, f16* __restrict__ ko)
{
    int it = blockIdx.x, b = blockIdx.y, which = blockIdx.z;
    const f16* wgt = which ? wk16 : wq16;
    const float* bias = which ? bk : bq;
    f16* outp = which ? ko : qo;
    int tid = threadIdx.x, w = tid >> 6, l = tid & 63;
    int l15 = l & 15, lhi = l >> 4;
    int i0 = it * 64 + w * 16;
    size_t arow = (size_t)(b * N_ + i0 + l15) * C_ + lhi * 8;
    f16v8 af[8];
    #pragma unroll
    for (int kk = 0; kk < 8; kk++) af[kk] = ldh(hn + arow + kk * 32);
    for (int oc = 0; oc < 16; oc++) {
        f32x4 acc = {0.f, 0.f, 0.f, 0.f};
        size_t wrow = (size_t)(oc * 16 + l15) * C_ + lhi * 8;
        #pragma unroll
        for (int kk = 0; kk < 8; kk++)
            acc = mfma16(af[kk], ldh(wgt + wrow + kk * 32), acc);
        float bia = bias[oc * 16 + l15];
        #pragma unroll
        for (int r = 0; r < 4; r++)
            outp[(size_t)(b * N_ + i0 + lhi * 4 + r) * C_ + oc * 16 + l15] =
                (f16)(acc[r] + bia);
    }
}

// ---------------- 3. v projection -> v^T [b][c][n] fp16 ----------------
__global__ __launch_bounds__(256) void proj_v_kernel(
    const f16* __restrict__ hn, const f16* __restrict__ wv16,
    const float* __restrict__ bv, f16* __restrict__ vT)
{
    int it = blockIdx.x, b = blockIdx.y;
    int tid = threadIdx.x, w = tid >> 6, l = tid & 63;
    int l15 = l & 15, lhi = l >> 4;
    int o0 = w * 64, i0 = it * 64;
    f32x4 acc[4][4];
    #pragma unroll
    for (int mc = 0; mc < 4; mc++)
        #pragma unroll
        for (int nc = 0; nc < 4; nc++) acc[mc][nc] = (f32x4){0.f, 0.f, 0.f, 0.f};
    for (int kk = 0; kk < 8; kk++) {
        f16v8 af[4], bfv[4];
        #pragma unroll
        for (int mc = 0; mc < 4; mc++)
            af[mc] = ldh(wv16 + (size_t)(o0 + mc * 16 + l15) * C_ + kk * 32 + lhi * 8);
        #pragma unroll
        for (int nc = 0; nc < 4; nc++)
            bfv[nc] = ldh(hn + (size_t)(b * N_ + i0 + nc * 16 + l15) * C_ + kk * 32 + lhi * 8);
        #pragma unroll
        for (int mc = 0; mc < 4; mc++)
            #pragma unroll
            for (int nc = 0; nc < 4; nc++)
                acc[mc][nc] = mfma16(af[mc], bfv[nc], acc[mc][nc]);
    }
    #pragma unroll
    for (int mc = 0; mc < 4; mc++) {
        float bia[4];
        #pragma unroll
        for (int r = 0; r < 4; r++) bia[r] = bv[o0 + mc * 16 + lhi * 4 + r];
        #pragma unroll
        for (int nc = 0; nc < 4; nc++)
            #pragma unroll
            for (int r = 0; r < 4; r++) {
                int o = o0 + mc * 16 + lhi * 4 + r;
                int i = i0 + nc * 16 + l15;
                vT[(size_t)(b * C_ + o) * N_ + i] = (f16)(acc[mc][nc][r] + bia[r]);
            }
    }
}

// ---------------- 4. flash attention: swapped QK^T, coalesced staging -------
// K tile [32][256]: chunks of 2 rows x 512B contiguous; XOR ((row&7)<<4) via
// pre-swizzled SOURCE; swizzled read. (round-7 proven)
__device__ __forceinline__ void stage_k(const f16* kbase, f16* dst, int j0,
                                        int w, int l) {
    #pragma unroll
    for (int rd = 0; rd < 4; rd++) {
        int cb = (rd * 4 + w) * 64;          // wave-uniform chunk base
        int mc = cb + l;                     // this lane's 16B chunk
        int row = mc >> 5;                   // 32 chunks (512B) per row
        int xoff = ((mc & 31) << 4) ^ ((row & 7) << 4);
        const f16* gsrc = kbase + (size_t)(j0 + row) * C_ + (xoff >> 1);
        __builtin_amdgcn_global_load_lds(
            (const __attribute__((address_space(1))) void*)gsrc,
            (__attribute__((address_space(3))) void*)(dst + (size_t)cb * 8),
            16, 0, 0);
    }
}
// V tile [256][32] (64B rows): within-row 16B-unit XOR ((row>>1)&3) applied on
// the SOURCE col — same 64B region per row (coalescing preserved), read uses
// lhi ^ ((l15>>1)&3) -> canonical conflict-free b128 histogram.
__device__ __forceinline__ void stage_v(const f16* vbase, f16* dst, int j0,
                                        int w, int l) {
    int tid = w * 64 + l;
    int colu = ((l & 3) ^ ((l >> 3) & 3)) * 8;   // swizzled 16B unit in row
    #pragma unroll
    for (int s = 0; s < 4; s++) {
        int cb = s * 256 + w * 64;           // wave-uniform chunk base
        const f16* gsrc = vbase + (size_t)(s * 64 + (tid >> 2)) * N_ + j0 + colu;
        __builtin_amdgcn_global_load_lds(
            (const __attribute__((address_space(1))) void*)gsrc,
            (__attribute__((address_space(3))) void*)(dst + (size_t)cb * 8),
            16, 0, 0);
    }
}

__global__ __launch_bounds__(256, 2) void flash_split_kernel(
    const f16* __restrict__ q, const f16* __restrict__ k,
    const f16* __restrict__ vT,
    f16* __restrict__ o0p, f16* __restrict__ o1p,
    float2* __restrict__ stats)
{
    // XCD-pinned: linear id % 8 -> XCD; group = (b,split), 2MB K/V L2-resident.
    int bi = blockIdx.x;
    int g = bi & 7;
    int it = bi >> 3;                 // 0..63
    int b = g >> 1, split = g & 1;
    int tid = threadIdx.x, w = tid >> 6, l = tid & 63;
    int l15 = l & 15, lhi = l >> 4;
    int i0 = it * 64 + w * 16;
    int jt0 = split * JT_PER;
    __shared__ __align__(16) f16 kb[2][32][256];     // 32 KB, XOR-swizzled
    __shared__ __align__(16) f16 vb[2][256][32];     // 32 KB, unit-swizzled
    __shared__ __align__(16) unsigned int Plds[4][16][20];  // 5 KB

    const f16* kbase = k + (size_t)b * N_ * C_;
    const f16* vbase = vT + (size_t)b * C_ * N_;

    f16v8 qf[8];
    size_t qrow = (size_t)(b * N_ + i0 + l15) * C_ + lhi * 8;
    #pragma unroll
    for (int kk = 0; kk < 8; kk++) qf[kk] = ldh(q + qrow + kk * 32);

    // oacc[cc][r] = O^T[c = cc*16 + lhi*4 + r][i = i0 + l15]
    f32x4 oacc[16];
    #pragma unroll
    for (int cc = 0; cc < 16; cc++) oacc[cc] = (f32x4){0.f, 0.f, 0.f, 0.f};
    float m = -1e30f, rsum = 0.f;    // per-lane: row i = i0 + l15

    int lhiV = lhi ^ ((l15 >> 1) & 3);   // V read 16B-unit after swizzle

    stage_k(kbase, &kb[0][0][0], jt0 * 32, w, l);
    stage_v(vbase, &vb[0][0][0], jt0 * 32, w, l);
    __syncthreads();

    for (int jt = 0; jt < JT_PER; jt++) {
        int cur = jt & 1;
        int j0 = (jt0 + jt) * 32;

        if (jt + 1 < JT_PER) {
            stage_k(kbase, &kb[cur ^ 1][0][0], j0 + 32, w, l);
            stage_v(vbase, &vb[cur ^ 1][0][0], j0 + 32, w, l);
        }

        // ---- swapped QK^T: s'[j][i] = mfma(K, Q) ----
        const char* kbc = (const char*)&kb[cur][0][0];
        f32x4 s0 = {0.f, 0.f, 0.f, 0.f};
        f32x4 s1 = {0.f, 0.f, 0.f, 0.f};
        #pragma unroll
        for (int kk = 0; kk < 8; kk++) {
            {
                int row = l15;
                int off = row * 512 + ((kk * 64 + lhi * 16) ^ ((row & 7) << 4));
                f16v8 kf = *reinterpret_cast<const f16v8*>(kbc + off);
                s0 = mfma16(kf, qf[kk], s0);
            }
            {
                int row = 16 + l15;
                int off = row * 512 + ((kk * 64 + lhi * 16) ^ ((row & 7) << 4));
                f16v8 kf = *reinterpret_cast<const f16v8*>(kbc + off);
                s1 = mfma16(kf, qf[kk], s1);
            }
        }

        // ---- per-lane online softmax with defer-max (THR=8) ----
        float mt = fmaxf(fmaxf(fmaxf(s0[0], s0[1]), fmaxf(s0[2], s0[3])),
                         fmaxf(fmaxf(s1[0], s1[1]), fmaxf(s1[2], s1[3])));
        mt = fmaxf(mt, __shfl_xor(mt, 16));
        mt = fmaxf(mt, __shfl_xor(mt, 32));
        if (!__all(mt <= m + 8.f)) {
            float mn = fmaxf(m, mt);
            float sc = __expf(m - mn);
            m = mn;
            rsum *= sc;
            #pragma unroll
            for (int cc = 0; cc < 16; cc++) {
                #pragma unroll
                for (int r = 0; r < 4; r++) oacc[cc][r] *= sc;
            }
        }
        float p0[4], p1[4];
        float ls = 0.f;
        #pragma unroll
        for (int r = 0; r < 4; r++) {
            p0[r] = __expf(s0[r] - m);
            p1[r] = __expf(s1[r] - m);
            ls += p0[r] + p1[r];
        }
        rsum += ls;

        // ---- P' -> LDS transposed (wave-local; lgkm-ordered, no barrier) ----
        uint2 pa = {pkh(p0[0], p0[1]), pkh(p0[2], p0[3])};
        uint2 pb = {pkh(p1[0], p1[1]), pkh(p1[2], p1[3])};
        *reinterpret_cast<uint2*>(&Plds[w][l15][lhi * 2])     = pa;
        *reinterpret_cast<uint2*>(&Plds[w][l15][8 + lhi * 2]) = pb;
        f16v8 pfB = *reinterpret_cast<const f16v8*>(&Plds[w][l15][lhi * 4]);

        // ---- O^T += V^T @ P' (swizzled V read, ~conflict-free) ----
        const f16* vbc = &vb[cur][0][0];
        #pragma unroll
        for (int cc = 0; cc < 16; cc++) {
            f16v8 vf = ldh(vbc + (cc * 16 + l15) * 32 + lhiV * 8);
            oacc[cc] = mfma16(vf, pfB, oacc[cc]);
        }

        __syncthreads();   // drains stage(jt+1) vmcnt; WAR guard for cur buffers
    }

    // final cross-lane lsum reduce (4 lanes share row i)
    rsum += __shfl_xor(rsum, 16);
    rsum += __shfl_xor(rsum, 32);
    float inv = 1.f / rsum;

    f16* op = split ? o1p : o0p;
    size_t obase = (size_t)(b * N_ + i0 + l15) * C_;
    #pragma unroll
    for (int cc = 0; cc < 16; cc++) {
        uint2 st = {pkh(oacc[cc][0] * inv, oacc[cc][1] * inv),
                    pkh(oacc[cc][2] * inv, oacc[cc][3] * inv)};
        *reinterpret_cast<uint2*>(op + obase + cc * 16 + lhi * 4) = st;
    }
    if (lhi == 0)
        stats[((size_t)split * B_ + b) * N_ + i0 + l15] = make_float2(m, rsum);
}

// ---------------- 5. fused combine + conv_o + bias + residual ----------------
__global__ __launch_bounds__(256) void final_kernel(
    const f16* __restrict__ o0p, const f16* __restrict__ o1p,
    const float2* __restrict__ stats, const f16* __restrict__ wo16,
    const float* __restrict__ bo, const float* __restrict__ x,
    float* __restrict__ out)
{
    int it = blockIdx.x, b = blockIdx.y;
    int tid = threadIdx.x, w = tid >> 6, l = tid & 63;
    int l15 = l & 15, lhi = l >> 4;
    int o0 = w * 64, i0 = it * 64;

    // per-row split weights (row = i0 + nc*16 + l15)
    f16 w0h[4], w1h[4];
    #pragma unroll
    for (int nc = 0; nc < 4; nc++) {
        int row = i0 + nc * 16 + l15;
        float2 s0 = stats[(size_t)b * N_ + row];
        float2 s1 = stats[((size_t)B_ + b) * N_ + row];
        float M = fmaxf(s0.x, s1.x);
        float a0 = s0.y * __expf(s0.x - M);
        float a1 = s1.y * __expf(s1.x - M);
        float inv = 1.f / (a0 + a1);
        w0h[nc] = (f16)(a0 * inv);
        w1h[nc] = (f16)(a1 * inv);
    }

    f32x4 acc[4][4];
    #pragma unroll
    for (int mc = 0; mc < 4; mc++)
        #pragma unroll
        for (int nc = 0; nc < 4; nc++) acc[mc][nc] = (f32x4){0.f, 0.f, 0.f, 0.f};
    for (int kk = 0; kk < 8; kk++) {
        f16v8 af[4], bfv[4];
        #pragma unroll
        for (int mc = 0; mc < 4; mc++)
            af[mc] = ldh(wo16 + (size_t)(o0 + mc * 16 + l15) * C_ + kk * 32 + lhi * 8);
        #pragma unroll
        for (int nc = 0; nc < 4; nc++) {
            size_t off = (size_t)(b * N_ + i0 + nc * 16 + l15) * C_ + kk * 32 + lhi * 8;
            f16v8 a = ldh(o0p + off);
            f16v8 c = ldh(o1p + off);
            bfv[nc] = a * w0h[nc] + c * w1h[nc];
        }
        #pragma unroll
        for (int mc = 0; mc < 4; mc++)
            #pragma unroll
            for (int nc = 0; nc < 4; nc++)
                acc[mc][nc] = mfma16(af[mc], bfv[nc], acc[mc][nc]);
    }
    #pragma unroll
    for (int mc = 0; mc < 4; mc++) {
        float bia[4];
        #pragma unroll
        for (int r = 0; r < 4; r++) bia[r] = bo[o0 + mc * 16 + lhi * 4 + r];
        #pragma unroll
        for (int nc = 0; nc < 4; nc++)
            #pragma unroll
            for (int r = 0; r < 4; r++) {
                int o = o0 + mc * 16 + lhi * 4 + r;
                int i = i0 + nc * 16 + l15;
                size_t idx = (size_t)(b * C_ + o) * N_ + i;
                out[idx] = x[idx] + acc[mc][nc][r] + bia[r];
            }
    }
}

extern "C" void kernel_launch(void* const* d_in, const int* in_sizes, int n_in,
                              void* d_out, int out_size, void* d_ws, size_t ws_size,
                              hipStream_t stream) {
    const float* x  = (const float*)d_in[0];
    const float* gg = (const float*)d_in[1];
    const float* gb = (const float*)d_in[2];
    const float* wq = (const float*)d_in[3];
    const float* bq = (const float*)d_in[4];
    const float* wk = (const float*)d_in[5];
    const float* bk = (const float*)d_in[6];
    const float* wv = (const float*)d_in[7];
    const float* bv = (const float*)d_in[8];
    const float* wo = (const float*)d_in[9];
    const float* bo = (const float*)d_in[10];
    float* out = (float*)d_out;

    char* p = (char*)d_ws;
    const size_t WSZ = (size_t)C_ * C_ * 2;       // 128 KB per fp16 weight
    const size_t HSZ = (size_t)B_ * N_ * C_ * 2;  // 8 MB per fp16 activation
    f16* wq16 = (f16*)p; p += WSZ;
    f16* wk16 = (f16*)p; p += WSZ;
    f16* wv16 = (f16*)p; p += WSZ;
    f16* wo16 = (f16*)p; p += WSZ;
    f16* hn   = (f16*)p; p += HSZ;
    f16* qo   = (f16*)p; p += HSZ;
    f16* ko   = (f16*)p; p += HSZ;
    f16* vt   = (f16*)p; p += HSZ;
    f16* o1p  = (f16*)p; p += HSZ;                // split-1 partial
    float2* stats = (float2*)p; p += (size_t)SPLITS * B_ * N_ * sizeof(float2);

    f16* o0p = hn;            // hn dead after projections; split-0 partial

    conv_w_kernel<<<dim3(C_ * C_ / 256), 256, 0, stream>>>(
        wq, wk, wv, wo, wq16, wk16, wv16, wo16);
    gn_kernel<<<dim3(B_ * NG_), 256, 0, stream>>>(x, gg, gb, hn);
    proj_qk_kernel<<<dim3(N_ / 64, B_, 2), 256, 0, stream>>>(
        hn, wq16, wk16, bq, bk, qo, ko);
    proj_v_kernel<<<dim3(N_ / 64, B_), 256, 0, stream>>>(hn, wv16, bv, vt);
    flash_split_kernel<<<dim3(N_ / 64 * B_ * SPLITS), 256, 0, stream>>>(
        qo, ko, vt, o0p, o1p, stats);
    final_kernel<<<dim3(N_ / 64, B_), 256, 0, stream>>>(
        o0p, o1p, stats, wo16, bo, x, out);
}